// Round 9
// baseline (135.301 us; speedup 1.0000x reference)
//
#include <hip/hip_runtime.h>
#include <hip/hip_bf16.h>
#include <math.h>

typedef unsigned short u16;
typedef unsigned int   u32;
typedef unsigned long long u64;

// ws layout (float offsets)
#define WS_W2    0        // 1152 u32: packed bf16 conv weights [c][r][6]
#define WS_B4    2304     // 4:    fc1_b fp32
#define WS_FCW   2308     // 512:  fc_w [oc][q] fp32   (16B aligned)
#define WS_FCB   2820     // 128:  fc_b fp32           (16B aligned)
#define WS_GATES 2948     // 64:   8 gates x (2x2 complex) = 8 floats each
#define WS_FLAG  3012     // 1:    1.0 = inputs are bf16, 0.0 = fp32

__device__ inline float bfbits2f(u32 lo16) {
    u32 u = lo16 << 16;
    return __builtin_bit_cast(float, u);
}
__device__ inline float bchi(u32 w) {   // high 16 bits as bf16 -> float
    return __builtin_bit_cast(float, w & 0xffff0000u);
}
__device__ inline float bclo(u32 w) {   // low 16 bits as bf16 -> float
    return __builtin_bit_cast(float, w << 16);
}
__device__ inline u16 f2bf(float f) {
    u32 u = __builtin_bit_cast(u32, f);
    u = u + 0x7fffu + ((u >> 16) & 1u);   // round-to-nearest-even
    return (u16)(u >> 16);
}
__device__ inline float ld_param(const void* p, int i, int isbf16) {
    return isbf16 ? bfbits2f(((const u16*)p)[i]) : ((const float*)p)[i];
}

// ---------------- K0: sniff dtype, pack weights, build gate matrices -------
__global__ __launch_bounds__(256) void k0_prep(
        const void* __restrict__ x,
        const void* __restrict__ fc1_w, const void* __restrict__ fc1_b,
        const void* __restrict__ u3p,   const void* __restrict__ cu3p,
        const void* __restrict__ fc_w,  const void* __restrict__ fc_b,
        float* __restrict__ ws) {
    __shared__ int sflag;
    int t = threadIdx.x;
    if (t == 0) {
        // bf16-pair data: bits 14:7 of each u32 are a bf16 exponent, ~always
        // in [110,130] for N(0,1). fp32 data: those are mantissa bits (~8%).
        const u32* xw = (const u32*)x;
        int cnt = 0;
        for (int i = 0; i < 64; ++i) {
            u32 e = (xw[i] >> 7) & 0xFFu;
            if (e >= 110 && e <= 130) ++cnt;
        }
        sflag = (cnt >= 32) ? 1 : 0;
        ws[WS_FLAG] = (float)sflag;
    }
    __syncthreads();
    const int bf = sflag;
    // packed conv weights: u32[c][r][6]; u32 p packs (q,dj) pairs q-major:
    // idx = q*3+dj; lo16 = bf16(w[idx=2p]), hi16 = bf16(w[idx=2p+1])
    u32* wpk = (u32*)ws + WS_W2;
    for (int idx = t; idx < 1152; idx += 256) {
        int c = idx / 18;
        int rem = idx - c * 18;
        int r = rem / 6;
        int p = rem - r * 6;
        int i0 = 2 * p, i1 = 2 * p + 1;
        int q0 = i0 / 3, d0 = i0 - 3 * q0;
        int q1 = i1 / 3, d1 = i1 - 3 * q1;
        u32 lo = f2bf(ld_param(fc1_w, q0 * 576 + c * 9 + r * 3 + d0, bf));
        u32 hi = f2bf(ld_param(fc1_w, q1 * 576 + c * 9 + r * 3 + d1, bf));
        wpk[idx] = lo | (hi << 16);
    }
    if (t < 4)   ws[WS_B4 + t] = ld_param(fc1_b, t, bf);
    for (int idx = t; idx < 512; idx += 256) ws[WS_FCW + idx] = ld_param(fc_w, idx, bf);
    if (t < 128) ws[WS_FCB + t] = ld_param(fc_b, t, bf);
    if (t < 8) {
        int w = t & 3;
        const void* p = (t < 4) ? u3p : cu3p;
        float th = ld_param(p, w * 3 + 0, bf);
        float ph = ld_param(p, w * 3 + 1, bf);
        float la = ld_param(p, w * 3 + 2, bf);
        float c = cosf(0.5f * th), s = sinf(0.5f * th);
        float cl = cosf(la), sl = sinf(la);
        float cp = cosf(ph), sp = sinf(ph);
        float cpl = cp * cl - sp * sl, spl = sp * cl + cp * sl;
        float* m = ws + WS_GATES + t * 8;
        // U3 = [[cosT, -e^{i la} sinT], [e^{i ph} sinT, e^{i(ph+la)} cosT]]
        m[0] = c;        m[1] = 0.f;
        m[2] = -cl * s;  m[3] = -sl * s;
        m[4] = cp * s;   m[5] = sp * s;
        m[6] = cpl * c;  m[7] = spl * c;
    }
}

// ---------------- KF: fused conv + reduce + circuit + FC -------------------
// grid 1024 = (b:16) x (row:64); block 1024 = (tcg:16 waves, j:64 cols).
// Wave tcg reduces channels tcg*4..+3; weights read per-channel as 18 u32
// scalar loads (unroll 1 -> only 18 SGPRs live; NO scratch demotion — R8's
// w72[72] spilled to scratch: WRITE_SIZE 45.6 MB, VALUBusy 20%).
// In-LDS cross-wave reduction (aliases tile); circuit on wave 0; coalesced
// 1-uint4/thread FC epilogue. 2 blocks/CU -> 32 waves/CU.
__global__ __launch_bounds__(1024, 8) void kF(
        const void* __restrict__ x, const float* __restrict__ ws,
        void* __restrict__ out) {
    __shared__ u32 tile[192 * 34];   // [r*64+c][pair], 26112 B
    __shared__ float4 smEz[64];      // 1 KB
    float4* red = (float4*)tile;     // alias: 1024 float4 = 16 KB (<26112)

    const int t = threadIdx.x;
    const int bid = blockIdx.x;
    const int b = bid >> 6, row = bid & 63;
    const int bf = (ws[WS_FLAG] != 0.0f) ? 1 : 0;   // uniform
    const int tcg = t >> 6, j = t & 63;

    const u32*    xu = (const u32*)x;     // bf16 pair view
    const float2* xf = (const float2*)x;  // fp32 pair view
    const int xbase = b * 131072;         // per-image pairs

    // ---- stage 192 (r,c)-rows x 32 pairs = 6144 pairs, 6 per thread ------
    {
        const int jj = t & 31;
        const int seed = t >> 5;          // 0..31
#pragma unroll
        for (int i = 0; i < 6; ++i) {
            int rc = seed + i * 32;       // 0..191 = r*64 + c
            int r = rc >> 6, c = rc & 63;
            int gr = row - 1 + r;
            u32 pk = 0;
            if (gr >= 0 && gr < 64) {
                int idx = xbase + c * 2048 + gr * 32 + jj;
                if (bf) pk = xu[idx];
                else { float2 v = xf[idx];
                       pk = (u32)f2bf(v.x) | ((u32)f2bf(v.y) << 16); }
            }
            tile[rc * 34 + 1 + jj] = pk;
        }
        if (t < 384) { int rc = t >> 1; tile[rc * 34 + ((t & 1) ? 33 : 0)] = 0u; }
    }
    __syncthreads();

    // ---- conv: thread (j, tcg) reduces channels tcg*4 .. tcg*4+3 ---------
    const int pj = (j + 1) >> 1;          // first u32 of the 2 needed
    const int sh = (1 - (j & 1)) * 16;    // even j: drop leading col
    float ang0 = 0.f, ang1 = 0.f, ang2 = 0.f, ang3 = 0.f;
#pragma unroll 1
    for (int cc = 0; cc < 4; ++cc) {
        const int c = tcg * 4 + cc;
        // wave-uniform channel: 18 u32 weights via s_load (18 SGPRs live)
        const int cs = __builtin_amdgcn_readfirstlane(c);
        const u32* wp = (const u32*)ws + WS_W2 + cs * 18;
        u32 w18[18];
#pragma unroll
        for (int i = 0; i < 18; ++i) w18[i] = wp[i];
#pragma unroll
        for (int r = 0; r < 3; ++r) {
            const u32* rp = tile + (r * 64 + c) * 34 + pj;
            u32 lo = rp[0], hi = rp[1];           // ds_read2_b32
            u64 v = (((u64)hi << 32) | lo) >> sh;
            u32 vlo = (u32)v, vhi = (u32)(v >> 32);
            float e0 = bclo(vlo);                 // col j-1
            float e1 = bchi(vlo);                 // col j
            float e2 = bclo(vhi);                 // col j+1
            u32 u0 = w18[r * 6],     u1 = w18[r * 6 + 1], u2 = w18[r * 6 + 2];
            u32 u3 = w18[r * 6 + 3], u4 = w18[r * 6 + 4], u5 = w18[r * 6 + 5];
            // SALU unpack; v_fmac takes SGPR operand
            ang0 += e0 * bclo(u0) + e1 * bchi(u0) + e2 * bclo(u1);
            ang1 += e0 * bchi(u1) + e1 * bclo(u2) + e2 * bchi(u2);
            ang2 += e0 * bclo(u3) + e1 * bchi(u3) + e2 * bclo(u4);
            ang3 += e0 * bchi(u4) + e1 * bclo(u5) + e2 * bchi(u5);
        }
    }

    // ---- cross-wave reduction in LDS (alias tile) ------------------------
    __syncthreads();                 // conv reads of tile done
    red[tcg * 64 + j] = make_float4(ang0, ang1, ang2, ang3);
    __syncthreads();

    if (t < 64) {
        float ax = 0.f, ay = 0.f, az = 0.f, aw = 0.f;
#pragma unroll
        for (int g = 0; g < 16; ++g) {
            float4 a = red[g * 64 + t];
            ax += a.x; ay += a.y; az += a.z; aw += a.w;
        }
        float angf[4];
        angf[0] = ws[WS_B4 + 0] + ax;
        angf[1] = ws[WS_B4 + 1] + ay;
        angf[2] = ws[WS_B4 + 2] + az;
        angf[3] = ws[WS_B4 + 3] + aw;

        // ---- quantum circuit: product state after RY+U3, CU3 ring, <Z> ----
        const float* G = ws + WS_GATES;
        float vr[4][2], vi[4][2];
#pragma unroll
        for (int w = 0; w < 4; ++w) {
            float sa, ca;
            __sincosf(0.5f * angf[w], &sa, &ca);   // RY|0> = (cos, sin)
            const float* m = G + w * 8;
            vr[w][0] = m[0] * ca + m[2] * sa;  vi[w][0] = m[1] * ca + m[3] * sa;
            vr[w][1] = m[4] * ca + m[6] * sa;  vi[w][1] = m[5] * ca + m[7] * sa;
        }
        float t01r[4], t01i[4], t23r[4], t23i[4];
#pragma unroll
        for (int a = 0; a < 2; ++a)
#pragma unroll
            for (int bq = 0; bq < 2; ++bq) {
                t01r[a * 2 + bq] = vr[0][a] * vr[1][bq] - vi[0][a] * vi[1][bq];
                t01i[a * 2 + bq] = vr[0][a] * vi[1][bq] + vi[0][a] * vr[1][bq];
                t23r[a * 2 + bq] = vr[2][a] * vr[3][bq] - vi[2][a] * vi[3][bq];
                t23i[a * 2 + bq] = vr[2][a] * vi[3][bq] + vi[2][a] * vr[3][bq];
            }
        float ar[16], ai[16];   // amp index n = q0*8 + q1*4 + q2*2 + q3
#pragma unroll
        for (int n = 0; n < 16; ++n) {
            int hi = n >> 2, lo = n & 3;
            ar[n] = t01r[hi] * t23r[lo] - t01i[hi] * t23i[lo];
            ai[n] = t01r[hi] * t23i[lo] + t01i[hi] * t23r[lo];
        }
        // CU3 ring: control w, target (w+1)%4; U on control==1 subspace
#pragma unroll
        for (int w = 0; w < 4; ++w) {
            const float* m = G + 32 + w * 8;
            const int cb = 8 >> w;
            const int tb = 8 >> ((w + 1) & 3);
#pragma unroll
            for (int n = 0; n < 16; ++n) {
                if ((n & cb) != 0 && (n & tb) == 0) {
                    int n1 = n | tb;
                    float a0r = ar[n], a0i = ai[n], a1r = ar[n1], a1i = ai[n1];
                    ar[n]  = m[0] * a0r - m[1] * a0i + m[2] * a1r - m[3] * a1i;
                    ai[n]  = m[0] * a0i + m[1] * a0r + m[2] * a1i + m[3] * a1r;
                    ar[n1] = m[4] * a0r - m[5] * a0i + m[6] * a1r - m[7] * a1i;
                    ai[n1] = m[4] * a0i + m[5] * a0r + m[6] * a1i + m[7] * a1r;
                }
            }
        }
        float ez0 = 0.f, ez1 = 0.f, ez2 = 0.f, ez3 = 0.f;
#pragma unroll
        for (int n = 0; n < 16; ++n) {
            float pr = ar[n] * ar[n] + ai[n] * ai[n];
            ez0 += (n & 8) ? -pr : pr;
            ez1 += (n & 4) ? -pr : pr;
            ez2 += (n & 2) ? -pr : pr;
            ez3 += (n & 1) ? -pr : pr;
        }
        smEz[t] = make_float4(ez0, ez1, ez2, ez3);
    }
    __syncthreads();

    // ---- FC epilogue: thread -> (pixel p = t>>4, oc group og = (t&15)*8) --
    // consecutive lanes store consecutive uint4 (coalesced 1 KB / instr)
    {
        const float4 ez = smEz[t >> 4];
        const float4* fw4 = (const float4*)(ws + WS_FCW) + (t & 15) * 8;
        const float*  fbp = ws + WS_FCB + (t & 15) * 8;
        float v[8];
#pragma unroll
        for (int m = 0; m < 8; ++m) {
            float4 w = fw4[m];
            v[m] = fbp[m] + ez.x * w.x + ez.y * w.y + ez.z * w.z + ez.w * w.w;
        }
        if (bf) {
            u32 p0 = (u32)f2bf(v[0]) | ((u32)f2bf(v[1]) << 16);
            u32 p1 = (u32)f2bf(v[2]) | ((u32)f2bf(v[3]) << 16);
            u32 p2 = (u32)f2bf(v[4]) | ((u32)f2bf(v[5]) << 16);
            u32 p3 = (u32)f2bf(v[6]) | ((u32)f2bf(v[7]) << 16);
            ((uint4*)out)[bid * 1024 + t] = make_uint4(p0, p1, p2, p3);
        } else {
            float4* o = (float4*)out + (bid * 2048 + 2 * t);
            o[0] = make_float4(v[0], v[1], v[2], v[3]);
            o[1] = make_float4(v[4], v[5], v[6], v[7]);
        }
    }
}

extern "C" void kernel_launch(void* const* d_in, const int* in_sizes, int n_in,
                              void* d_out, int out_size, void* d_ws, size_t ws_size,
                              hipStream_t stream) {
    float* ws = (float*)d_ws;
    k0_prep<<<dim3(1), dim3(256), 0, stream>>>(d_in[0], d_in[1], d_in[2], d_in[3],
                                               d_in[4], d_in[5], d_in[6], ws);
    kF<<<dim3(1024), dim3(1024), 0, stream>>>(d_in[0], ws, d_out);
}

// Round 10
// 116.886 us; speedup vs baseline: 1.1575x; 1.1575x over previous
//
#include <hip/hip_runtime.h>
#include <hip/hip_bf16.h>
#include <math.h>

typedef unsigned short u16;
typedef unsigned int   u32;
typedef unsigned long long u64;

// ws layout (float offsets)
#define WS_W2    0        // 1152 u32: packed bf16 conv weights [c][r][6]
#define WS_B4    2304     // 4:    fc1_b fp32
#define WS_FCW   2308     // 512:  fc_w [oc][q] fp32   (16B aligned)
#define WS_FCB   2820     // 128:  fc_b fp32           (16B aligned)
#define WS_GATES 2948     // 64:   8 gates x (2x2 complex) = 8 floats each
#define WS_FLAG  3012     // 1:    1.0 = inputs are bf16, 0.0 = fp32

__device__ inline float bfbits2f(u32 lo16) {
    u32 u = lo16 << 16;
    return __builtin_bit_cast(float, u);
}
__device__ inline float bchi(u32 w) {   // high 16 bits as bf16 -> float
    return __builtin_bit_cast(float, w & 0xffff0000u);
}
__device__ inline float bclo(u32 w) {   // low 16 bits as bf16 -> float
    return __builtin_bit_cast(float, w << 16);
}
__device__ inline u16 f2bf(float f) {
    u32 u = __builtin_bit_cast(u32, f);
    u = u + 0x7fffu + ((u >> 16) & 1u);   // round-to-nearest-even
    return (u16)(u >> 16);
}
__device__ inline float ld_param(const void* p, int i, int isbf16) {
    return isbf16 ? bfbits2f(((const u16*)p)[i]) : ((const float*)p)[i];
}

// ---------------- K0: sniff dtype, pack weights, build gate matrices -------
__global__ __launch_bounds__(256) void k0_prep(
        const void* __restrict__ x,
        const void* __restrict__ fc1_w, const void* __restrict__ fc1_b,
        const void* __restrict__ u3p,   const void* __restrict__ cu3p,
        const void* __restrict__ fc_w,  const void* __restrict__ fc_b,
        float* __restrict__ ws) {
    __shared__ int sflag;
    int t = threadIdx.x;
    if (t == 0) {
        // bf16-pair data: bits 14:7 of each u32 are a bf16 exponent, ~always
        // in [110,130] for N(0,1). fp32 data: those are mantissa bits (~8%).
        const u32* xw = (const u32*)x;
        int cnt = 0;
        for (int i = 0; i < 64; ++i) {
            u32 e = (xw[i] >> 7) & 0xFFu;
            if (e >= 110 && e <= 130) ++cnt;
        }
        sflag = (cnt >= 32) ? 1 : 0;
        ws[WS_FLAG] = (float)sflag;
    }
    __syncthreads();
    const int bf = sflag;
    // packed conv weights: u32[c][r][6]; u32 p packs (q,dj) pairs q-major:
    // idx = q*3+dj; lo16 = bf16(w[idx=2p]), hi16 = bf16(w[idx=2p+1])
    u32* wpk = (u32*)ws + WS_W2;
    for (int idx = t; idx < 1152; idx += 256) {
        int c = idx / 18;
        int rem = idx - c * 18;
        int r = rem / 6;
        int p = rem - r * 6;
        int i0 = 2 * p, i1 = 2 * p + 1;
        int q0 = i0 / 3, d0 = i0 - 3 * q0;
        int q1 = i1 / 3, d1 = i1 - 3 * q1;
        u32 lo = f2bf(ld_param(fc1_w, q0 * 576 + c * 9 + r * 3 + d0, bf));
        u32 hi = f2bf(ld_param(fc1_w, q1 * 576 + c * 9 + r * 3 + d1, bf));
        wpk[idx] = lo | (hi << 16);
    }
    if (t < 4)   ws[WS_B4 + t] = ld_param(fc1_b, t, bf);
    for (int idx = t; idx < 512; idx += 256) ws[WS_FCW + idx] = ld_param(fc_w, idx, bf);
    if (t < 128) ws[WS_FCB + t] = ld_param(fc_b, t, bf);
    if (t < 8) {
        int w = t & 3;
        const void* p = (t < 4) ? u3p : cu3p;
        float th = ld_param(p, w * 3 + 0, bf);
        float ph = ld_param(p, w * 3 + 1, bf);
        float la = ld_param(p, w * 3 + 2, bf);
        float c = cosf(0.5f * th), s = sinf(0.5f * th);
        float cl = cosf(la), sl = sinf(la);
        float cp = cosf(ph), sp = sinf(ph);
        float cpl = cp * cl - sp * sl, spl = sp * cl + cp * sl;
        float* m = ws + WS_GATES + t * 8;
        // U3 = [[cosT, -e^{i la} sinT], [e^{i ph} sinT, e^{i(ph+la)} cosT]]
        m[0] = c;        m[1] = 0.f;
        m[2] = -cl * s;  m[3] = -sl * s;
        m[4] = cp * s;   m[5] = sp * s;
        m[6] = cpl * c;  m[7] = spl * c;
    }
}

// ---------------- KF: fused conv + reduce + circuit + FC -------------------
// grid 1024 = (b:16) x (row:64); block 512 = (tcg:8 waves, j:64 cols).
// Wave tcg reduces channels tcg*8..+7; per-channel 18-u32 scalar weights
// (18 SGPRs live). NO min-waves launch-bounds arg: R8/R9's (1024,8) made
// the allocator budget 32 VGPRs -> scratch spill (WRITE_SIZE 46 MB).
// Natural VGPR (~56) -> 4 blocks/CU = 32 waves/CU.
__global__ __launch_bounds__(512) void kF(
        const void* __restrict__ x, const float* __restrict__ ws,
        void* __restrict__ out) {
    __shared__ u32 tile[192 * 34];   // [r*64+c][pair], 26112 B
    __shared__ float4 smEz[64];      // 1 KB
    float4* red = (float4*)tile;     // alias: 512 float4 = 8 KB (<26112)

    const int t = threadIdx.x;
    const int bid = blockIdx.x;
    const int b = bid >> 6, row = bid & 63;
    const int bf = (ws[WS_FLAG] != 0.0f) ? 1 : 0;   // uniform
    const int tcg = t >> 6, j = t & 63;

    const u32*    xu = (const u32*)x;     // bf16 pair view
    const float2* xf = (const float2*)x;  // fp32 pair view
    const int xbase = b * 131072;         // per-image pairs

    // ---- stage 192 (r,c)-rows x 32 pairs = 6144 pairs, 12 per thread -----
    {
        const int jj = t & 31;
        const int seed = t >> 5;          // 0..15
#pragma unroll
        for (int i = 0; i < 12; ++i) {
            int rc = seed + i * 16;       // 0..191 = r*64 + c
            int r = rc >> 6, c = rc & 63;
            int gr = row - 1 + r;
            u32 pk = 0;
            if (gr >= 0 && gr < 64) {
                int idx = xbase + c * 2048 + gr * 32 + jj;
                if (bf) pk = xu[idx];
                else { float2 v = xf[idx];
                       pk = (u32)f2bf(v.x) | ((u32)f2bf(v.y) << 16); }
            }
            tile[rc * 34 + 1 + jj] = pk;
        }
        if (t < 384) { int rc = t >> 1; tile[rc * 34 + ((t & 1) ? 33 : 0)] = 0u; }
    }
    __syncthreads();

    // ---- conv: thread (j, tcg) reduces channels tcg*8 .. tcg*8+7 ---------
    const int pj = (j + 1) >> 1;          // first u32 of the 2 needed
    const int sh = (1 - (j & 1)) * 16;    // even j: drop leading col
    float ang0 = 0.f, ang1 = 0.f, ang2 = 0.f, ang3 = 0.f;
#pragma unroll 1
    for (int cc = 0; cc < 8; ++cc) {
        const int c = tcg * 8 + cc;
        // wave-uniform channel: 18 u32 weights via s_load (18 SGPRs live)
        const int cs = __builtin_amdgcn_readfirstlane(c);
        const u32* wp = (const u32*)ws + WS_W2 + cs * 18;
        u32 w18[18];
#pragma unroll
        for (int i = 0; i < 18; ++i) w18[i] = wp[i];
#pragma unroll
        for (int r = 0; r < 3; ++r) {
            const u32* rp = tile + (r * 64 + c) * 34 + pj;
            u32 lo = rp[0], hi = rp[1];           // ds_read2_b32
            u64 v = (((u64)hi << 32) | lo) >> sh;
            u32 vlo = (u32)v, vhi = (u32)(v >> 32);
            float e0 = bclo(vlo);                 // col j-1
            float e1 = bchi(vlo);                 // col j
            float e2 = bclo(vhi);                 // col j+1
            u32 u0 = w18[r * 6],     u1 = w18[r * 6 + 1], u2 = w18[r * 6 + 2];
            u32 u3 = w18[r * 6 + 3], u4 = w18[r * 6 + 4], u5 = w18[r * 6 + 5];
            // SALU unpack; v_fmac takes SGPR operand
            ang0 += e0 * bclo(u0) + e1 * bchi(u0) + e2 * bclo(u1);
            ang1 += e0 * bchi(u1) + e1 * bclo(u2) + e2 * bchi(u2);
            ang2 += e0 * bclo(u3) + e1 * bchi(u3) + e2 * bclo(u4);
            ang3 += e0 * bchi(u4) + e1 * bclo(u5) + e2 * bchi(u5);
        }
    }

    // ---- cross-wave reduction in LDS (alias tile) ------------------------
    __syncthreads();                 // conv reads of tile done
    red[tcg * 64 + j] = make_float4(ang0, ang1, ang2, ang3);
    __syncthreads();

    if (t < 64) {
        float ax = 0.f, ay = 0.f, az = 0.f, aw = 0.f;
#pragma unroll
        for (int g = 0; g < 8; ++g) {
            float4 a = red[g * 64 + t];
            ax += a.x; ay += a.y; az += a.z; aw += a.w;
        }
        float angf[4];
        angf[0] = ws[WS_B4 + 0] + ax;
        angf[1] = ws[WS_B4 + 1] + ay;
        angf[2] = ws[WS_B4 + 2] + az;
        angf[3] = ws[WS_B4 + 3] + aw;

        // ---- quantum circuit: product state after RY+U3, CU3 ring, <Z> ----
        const float* G = ws + WS_GATES;
        float vr[4][2], vi[4][2];
#pragma unroll
        for (int w = 0; w < 4; ++w) {
            float sa, ca;
            __sincosf(0.5f * angf[w], &sa, &ca);   // RY|0> = (cos, sin)
            const float* m = G + w * 8;
            vr[w][0] = m[0] * ca + m[2] * sa;  vi[w][0] = m[1] * ca + m[3] * sa;
            vr[w][1] = m[4] * ca + m[6] * sa;  vi[w][1] = m[5] * ca + m[7] * sa;
        }
        float t01r[4], t01i[4], t23r[4], t23i[4];
#pragma unroll
        for (int a = 0; a < 2; ++a)
#pragma unroll
            for (int bq = 0; bq < 2; ++bq) {
                t01r[a * 2 + bq] = vr[0][a] * vr[1][bq] - vi[0][a] * vi[1][bq];
                t01i[a * 2 + bq] = vr[0][a] * vi[1][bq] + vi[0][a] * vr[1][bq];
                t23r[a * 2 + bq] = vr[2][a] * vr[3][bq] - vi[2][a] * vi[3][bq];
                t23i[a * 2 + bq] = vr[2][a] * vi[3][bq] + vi[2][a] * vr[3][bq];
            }
        float ar[16], ai[16];   // amp index n = q0*8 + q1*4 + q2*2 + q3
#pragma unroll
        for (int n = 0; n < 16; ++n) {
            int hi = n >> 2, lo = n & 3;
            ar[n] = t01r[hi] * t23r[lo] - t01i[hi] * t23i[lo];
            ai[n] = t01r[hi] * t23i[lo] + t01i[hi] * t23r[lo];
        }
        // CU3 ring: control w, target (w+1)%4; U on control==1 subspace
#pragma unroll
        for (int w = 0; w < 4; ++w) {
            const float* m = G + 32 + w * 8;
            const int cb = 8 >> w;
            const int tb = 8 >> ((w + 1) & 3);
#pragma unroll
            for (int n = 0; n < 16; ++n) {
                if ((n & cb) != 0 && (n & tb) == 0) {
                    int n1 = n | tb;
                    float a0r = ar[n], a0i = ai[n], a1r = ar[n1], a1i = ai[n1];
                    ar[n]  = m[0] * a0r - m[1] * a0i + m[2] * a1r - m[3] * a1i;
                    ai[n]  = m[0] * a0i + m[1] * a0r + m[2] * a1i + m[3] * a1r;
                    ar[n1] = m[4] * a0r - m[5] * a0i + m[6] * a1r - m[7] * a1i;
                    ai[n1] = m[4] * a0i + m[5] * a0r + m[6] * a1i + m[7] * a1r;
                }
            }
        }
        float ez0 = 0.f, ez1 = 0.f, ez2 = 0.f, ez3 = 0.f;
#pragma unroll
        for (int n = 0; n < 16; ++n) {
            float pr = ar[n] * ar[n] + ai[n] * ai[n];
            ez0 += (n & 8) ? -pr : pr;
            ez1 += (n & 4) ? -pr : pr;
            ez2 += (n & 2) ? -pr : pr;
            ez3 += (n & 1) ? -pr : pr;
        }
        smEz[t] = make_float4(ez0, ez1, ez2, ez3);
    }
    __syncthreads();

    // ---- FC epilogue: 2 iterations; thread -> (pixel (t>>4)+ch*32,
    // oc group (t&15)*8); consecutive lanes store consecutive uint4 --------
    {
        const float4* fw4 = (const float4*)(ws + WS_FCW) + (t & 15) * 8;
        const float*  fbp = ws + WS_FCB + (t & 15) * 8;
        float4 w0 = fw4[0], w1 = fw4[1], w2 = fw4[2], w3 = fw4[3];
        float4 w4 = fw4[4], w5 = fw4[5], w6 = fw4[6], w7 = fw4[7];
#pragma unroll
        for (int ch = 0; ch < 2; ++ch) {
            const float4 ez = smEz[(t >> 4) + ch * 32];
            float v0 = fbp[0] + ez.x*w0.x + ez.y*w0.y + ez.z*w0.z + ez.w*w0.w;
            float v1 = fbp[1] + ez.x*w1.x + ez.y*w1.y + ez.z*w1.z + ez.w*w1.w;
            float v2 = fbp[2] + ez.x*w2.x + ez.y*w2.y + ez.z*w2.z + ez.w*w2.w;
            float v3 = fbp[3] + ez.x*w3.x + ez.y*w3.y + ez.z*w3.z + ez.w*w3.w;
            float v4 = fbp[4] + ez.x*w4.x + ez.y*w4.y + ez.z*w4.z + ez.w*w4.w;
            float v5 = fbp[5] + ez.x*w5.x + ez.y*w5.y + ez.z*w5.z + ez.w*w5.w;
            float v6 = fbp[6] + ez.x*w6.x + ez.y*w6.y + ez.z*w6.z + ez.w*w6.w;
            float v7 = fbp[7] + ez.x*w7.x + ez.y*w7.y + ez.z*w7.z + ez.w*w7.w;
            if (bf) {
                u32 p0 = (u32)f2bf(v0) | ((u32)f2bf(v1) << 16);
                u32 p1 = (u32)f2bf(v2) | ((u32)f2bf(v3) << 16);
                u32 p2 = (u32)f2bf(v4) | ((u32)f2bf(v5) << 16);
                u32 p3 = (u32)f2bf(v6) | ((u32)f2bf(v7) << 16);
                ((uint4*)out)[bid * 1024 + ch * 512 + t] =
                    make_uint4(p0, p1, p2, p3);
            } else {
                float4* o = (float4*)out + (bid * 2048 + ch * 1024 + 2 * t);
                o[0] = make_float4(v0, v1, v2, v3);
                o[1] = make_float4(v4, v5, v6, v7);
            }
        }
    }
}

extern "C" void kernel_launch(void* const* d_in, const int* in_sizes, int n_in,
                              void* d_out, int out_size, void* d_ws, size_t ws_size,
                              hipStream_t stream) {
    float* ws = (float*)d_ws;
    k0_prep<<<dim3(1), dim3(256), 0, stream>>>(d_in[0], d_in[1], d_in[2], d_in[3],
                                               d_in[4], d_in[5], d_in[6], ws);
    kF<<<dim3(1024), dim3(512), 0, stream>>>(d_in[0], ws, d_out);
}

// Round 11
// 109.324 us; speedup vs baseline: 1.2376x; 1.0692x over previous
//
#include <hip/hip_runtime.h>
#include <hip/hip_bf16.h>
#include <math.h>

typedef unsigned short u16;
typedef unsigned int   u32;
typedef unsigned long long u64;

// ws layout (float offsets)
#define WS_W2    0        // 1152 u32: packed bf16 conv weights [c][r][6]
#define WS_B4    2304     // 4:    fc1_b fp32
#define WS_FCW   2308     // 512:  fc_w [oc][q] fp32   (16B aligned)
#define WS_FCB   2820     // 128:  fc_b fp32           (16B aligned)
#define WS_GATES 2948     // 64:   8 gates x (2x2 complex) = 8 floats each
#define WS_FLAG  3012     // 1:    1.0 = inputs are bf16, 0.0 = fp32
#define WS_PART  4096     // float4[8][65536]: per-cg partial angles (8 MB)

__device__ inline float bfbits2f(u32 lo16) {
    u32 u = lo16 << 16;
    return __builtin_bit_cast(float, u);
}
__device__ inline float bchi(u32 w) {   // high 16 bits as bf16 -> float
    return __builtin_bit_cast(float, w & 0xffff0000u);
}
__device__ inline float bclo(u32 w) {   // low 16 bits as bf16 -> float
    return __builtin_bit_cast(float, w << 16);
}
__device__ inline u16 f2bf(float f) {
    u32 u = __builtin_bit_cast(u32, f);
    u = u + 0x7fffu + ((u >> 16) & 1u);   // round-to-nearest-even
    return (u16)(u >> 16);
}
__device__ inline float ld_param(const void* p, int i, int isbf16) {
    return isbf16 ? bfbits2f(((const u16*)p)[i]) : ((const float*)p)[i];
}

// ---------------- K0: sniff dtype, pack weights, build gate matrices -------
// grid 8: each block packs 144 of the 1152 weight words (each block sniffs
// the dtype itself — deterministic); block 0 also does bias/fc/gates.
__global__ __launch_bounds__(256) void k0_prep(
        const void* __restrict__ x,
        const void* __restrict__ fc1_w, const void* __restrict__ fc1_b,
        const void* __restrict__ u3p,   const void* __restrict__ cu3p,
        const void* __restrict__ fc_w,  const void* __restrict__ fc_b,
        float* __restrict__ ws) {
    __shared__ int sflag;
    const int t = threadIdx.x;
    const int bid = blockIdx.x;
    if (t == 0) {
        // bf16-pair data: bits 14:7 of each u32 are a bf16 exponent, ~always
        // in [110,130] for N(0,1). fp32 data: those are mantissa bits (~8%).
        const u32* xw = (const u32*)x;
        int cnt = 0;
        for (int i = 0; i < 64; ++i) {
            u32 e = (xw[i] >> 7) & 0xFFu;
            if (e >= 110 && e <= 130) ++cnt;
        }
        sflag = (cnt >= 32) ? 1 : 0;
        if (bid == 0) ws[WS_FLAG] = (float)sflag;
    }
    __syncthreads();
    const int bf = sflag;
    // packed conv weights: u32[c][r][6]; u32 p packs (q,dj) pairs q-major:
    // idx = q*3+dj; lo16 = bf16(w[idx=2p]), hi16 = bf16(w[idx=2p+1])
    if (t < 144) {
        int idx = bid * 144 + t;
        int c = idx / 18;
        int rem = idx - c * 18;
        int r = rem / 6;
        int p = rem - r * 6;
        int i0 = 2 * p, i1 = 2 * p + 1;
        int q0 = i0 / 3, d0 = i0 - 3 * q0;
        int q1 = i1 / 3, d1 = i1 - 3 * q1;
        u32 lo = f2bf(ld_param(fc1_w, q0 * 576 + c * 9 + r * 3 + d0, bf));
        u32 hi = f2bf(ld_param(fc1_w, q1 * 576 + c * 9 + r * 3 + d1, bf));
        ((u32*)ws + WS_W2)[idx] = lo | (hi << 16);
    }
    if (bid == 0) {
        if (t < 4)   ws[WS_B4 + t] = ld_param(fc1_b, t, bf);
        for (int idx = t; idx < 512; idx += 256) ws[WS_FCW + idx] = ld_param(fc_w, idx, bf);
        if (t < 128) ws[WS_FCB + t] = ld_param(fc_b, t, bf);
        if (t < 8) {
            int w = t & 3;
            const void* p = (t < 4) ? u3p : cu3p;
            float th = ld_param(p, w * 3 + 0, bf);
            float ph = ld_param(p, w * 3 + 1, bf);
            float la = ld_param(p, w * 3 + 2, bf);
            float c = cosf(0.5f * th), s = sinf(0.5f * th);
            float cl = cosf(la), sl = sinf(la);
            float cp = cosf(ph), sp = sinf(ph);
            float cpl = cp * cl - sp * sl, spl = sp * cl + cp * sl;
            float* m = ws + WS_GATES + t * 8;
            // U3 = [[cosT, -e^{i la} sinT], [e^{i ph} sinT, e^{i(ph+la)} cosT]]
            m[0] = c;        m[1] = 0.f;
            m[2] = -cl * s;  m[3] = -sl * s;
            m[4] = cp * s;   m[5] = sp * s;
            m[6] = cpl * c;  m[7] = spl * c;
        }
    }
}

// ---------------- KA: conv partials (R7 structure — measured best) ---------
// grid 8192 = (b:16) x (row:64) x (cg:8); block 256 = (j:64, tc:4).
// Wave's 2 channels' packed weights bulk-s_loaded into SGPRs BEFORE the
// barrier (no SMEM in the conv loop). 8 blocks/CU -> 32 waves/CU.
__global__ __launch_bounds__(256) void kA_conv(
        const void* __restrict__ x, const float* __restrict__ ws,
        float4* __restrict__ part) {
    __shared__ u32 tile[24 * 34];    // [r*8+cl][pair], 3264 B
    __shared__ float4 red4[256];     // 4 KB
    const int t = threadIdx.x;
    const int bid = blockIdx.x;
    const int cg  = bid & 7;
    const int row = (bid >> 3) & 63;
    const int b   = bid >> 9;
    const int bf = (ws[WS_FLAG] != 0.0f) ? 1 : 0;   // uniform
    const int c0 = cg * 8;
    const int tc = t >> 6;

    // ---- hoisted wave-uniform weight load: 36 u32 -> SGPRs (s_load) -------
    const int cs = __builtin_amdgcn_readfirstlane(c0 + tc * 2);
    const u32* wpk = (const u32*)ws + WS_W2 + cs * 18;
    u32 w36[36];
#pragma unroll
    for (int i = 0; i < 36; ++i) w36[i] = wpk[i];

    const u32*    xu = (const u32*)x;     // bf16 pair view
    const float2* xf = (const float2*)x;  // fp32 pair view
    const int xbase = b * 131072;         // per-image pairs

    // ---- stage 24 (r,cl)-rows x 32 pairs = 768 pairs, 3 per thread --------
    {
        const int jj = t & 31;
        const int g8 = t >> 5;            // 0..7
#pragma unroll
        for (int i = 0; i < 3; ++i) {
            int rowcl = g8 + i * 8;       // 0..23 = r*8 + cl
            int r = rowcl >> 3, cl = rowcl & 7;
            int gr = row - 1 + r;
            u32 pk = 0;
            if (gr >= 0 && gr < 64) {
                int idx = xbase + (c0 + cl) * 2048 + gr * 32 + jj;
                if (bf) pk = xu[idx];
                else { float2 v = xf[idx];
                       pk = (u32)f2bf(v.x) | ((u32)f2bf(v.y) << 16); }
            }
            tile[rowcl * 34 + 1 + jj] = pk;
        }
        if (t < 48) { int rc = t >> 1; tile[rc * 34 + ((t & 1) ? 33 : 0)] = 0u; }
    }
    __syncthreads();

    // ---- conv: thread (j, tc) reduces channels tc*2, tc*2+1 ---------------
    const int j = t & 63;
    const int pj = (j + 1) >> 1;          // first u32 of the 2 needed
    const int sh = (1 - (j & 1)) * 16;    // even j: drop leading col
    float ang0 = 0.f, ang1 = 0.f, ang2 = 0.f, ang3 = 0.f;
#pragma unroll
    for (int cc = 0; cc < 2; ++cc) {
        const int cl = tc * 2 + cc;
#pragma unroll
        for (int r = 0; r < 3; ++r) {
            const u32* rp = tile + (r * 8 + cl) * 34 + pj;
            u32 lo = rp[0], hi = rp[1];           // ds_read2_b32
            u64 v = (((u64)hi << 32) | lo) >> sh;
            u32 vlo = (u32)v, vhi = (u32)(v >> 32);
            float e0 = bclo(vlo);                 // col j-1
            float e1 = bchi(vlo);                 // col j
            float e2 = bclo(vhi);                 // col j+1
            const int wb = cc * 18 + r * 6;
            u32 u0 = w36[wb], u1 = w36[wb + 1], u2 = w36[wb + 2];
            u32 u3 = w36[wb + 3], u4 = w36[wb + 4], u5 = w36[wb + 5];
            // SALU unpack (s_lshl/s_and); v_fmac takes SGPR operand
            ang0 += e0 * bclo(u0) + e1 * bchi(u0) + e2 * bclo(u1);
            ang1 += e0 * bchi(u1) + e1 * bclo(u2) + e2 * bchi(u2);
            ang2 += e0 * bclo(u3) + e1 * bchi(u3) + e2 * bclo(u4);
            ang3 += e0 * bchi(u4) + e1 * bclo(u5) + e2 * bchi(u5);
        }
    }

    red4[tc * 64 + j] = make_float4(ang0, ang1, ang2, ang3);
    __syncthreads();
    if (t < 64) {
        float4 a0 = red4[t], a1 = red4[64 + t], a2 = red4[128 + t], a3 = red4[192 + t];
        float4 s = make_float4(a0.x + a1.x + a2.x + a3.x,
                               a0.y + a1.y + a2.y + a3.y,
                               a0.z + a1.z + a2.z + a3.z,
                               a0.w + a1.w + a2.w + a3.w);
        // [cg][pixel] layout: lane-consecutive 16B stores (coalesced)
        part[cg * 65536 + b * 4096 + row * 64 + t] = s;
    }
}

// ---------------- KB: reduce partials + circuit + output FC ----------------
// grid 1024; block 256. Parallel partial reduction: thread t loads 2 of the
// 8 partials for pixel (t&63) -> LDS tree (was: 8-deep serial chain on one
// thread). Wave 0 runs circuit; coalesced uint4 epilogue.
__global__ __launch_bounds__(256) void kB_circuit_fc(
        const float* __restrict__ ws, const float4* __restrict__ part,
        void* __restrict__ out) {
    __shared__ float4 red[256];
    __shared__ float4 smEz[64];
    const int t = threadIdx.x;
    const int bp0 = blockIdx.x * 64;
    const int bf = (ws[WS_FLAG] != 0.0f) ? 1 : 0;

    {
        const int g = t >> 6, p = t & 63;
        float4 a = part[(2 * g) * 65536 + bp0 + p];
        float4 c = part[(2 * g + 1) * 65536 + bp0 + p];
        red[t] = make_float4(a.x + c.x, a.y + c.y, a.z + c.z, a.w + c.w);
    }
    __syncthreads();

    if (t < 64) {
        float4 a0 = red[t], a1 = red[64 + t], a2 = red[128 + t], a3 = red[192 + t];
        float angf[4];
        angf[0] = ws[WS_B4 + 0] + a0.x + a1.x + a2.x + a3.x;
        angf[1] = ws[WS_B4 + 1] + a0.y + a1.y + a2.y + a3.y;
        angf[2] = ws[WS_B4 + 2] + a0.z + a1.z + a2.z + a3.z;
        angf[3] = ws[WS_B4 + 3] + a0.w + a1.w + a2.w + a3.w;

        // ---- quantum circuit: product state after RY+U3, CU3 ring, <Z> ----
        const float* G = ws + WS_GATES;
        float vr[4][2], vi[4][2];
#pragma unroll
        for (int w = 0; w < 4; ++w) {
            float sa, ca;
            __sincosf(0.5f * angf[w], &sa, &ca);   // RY|0> = (cos, sin)
            const float* m = G + w * 8;
            vr[w][0] = m[0] * ca + m[2] * sa;  vi[w][0] = m[1] * ca + m[3] * sa;
            vr[w][1] = m[4] * ca + m[6] * sa;  vi[w][1] = m[5] * ca + m[7] * sa;
        }
        float t01r[4], t01i[4], t23r[4], t23i[4];
#pragma unroll
        for (int a = 0; a < 2; ++a)
#pragma unroll
            for (int bq = 0; bq < 2; ++bq) {
                t01r[a * 2 + bq] = vr[0][a] * vr[1][bq] - vi[0][a] * vi[1][bq];
                t01i[a * 2 + bq] = vr[0][a] * vi[1][bq] + vi[0][a] * vr[1][bq];
                t23r[a * 2 + bq] = vr[2][a] * vr[3][bq] - vi[2][a] * vi[3][bq];
                t23i[a * 2 + bq] = vr[2][a] * vi[3][bq] + vi[2][a] * vr[3][bq];
            }
        float ar[16], ai[16];   // amp index n = q0*8 + q1*4 + q2*2 + q3
#pragma unroll
        for (int n = 0; n < 16; ++n) {
            int hi = n >> 2, lo = n & 3;
            ar[n] = t01r[hi] * t23r[lo] - t01i[hi] * t23i[lo];
            ai[n] = t01r[hi] * t23i[lo] + t01i[hi] * t23r[lo];
        }
        // CU3 ring: control w, target (w+1)%4; U on control==1 subspace
#pragma unroll
        for (int w = 0; w < 4; ++w) {
            const float* m = G + 32 + w * 8;
            const int cb = 8 >> w;
            const int tb = 8 >> ((w + 1) & 3);
#pragma unroll
            for (int n = 0; n < 16; ++n) {
                if ((n & cb) != 0 && (n & tb) == 0) {
                    int n1 = n | tb;
                    float a0r = ar[n], a0i = ai[n], a1r = ar[n1], a1i = ai[n1];
                    ar[n]  = m[0] * a0r - m[1] * a0i + m[2] * a1r - m[3] * a1i;
                    ai[n]  = m[0] * a0i + m[1] * a0r + m[2] * a1i + m[3] * a1r;
                    ar[n1] = m[4] * a0r - m[5] * a0i + m[6] * a1r - m[7] * a1i;
                    ai[n1] = m[4] * a0i + m[5] * a0r + m[6] * a1i + m[7] * a1r;
                }
            }
        }
        float ez0 = 0.f, ez1 = 0.f, ez2 = 0.f, ez3 = 0.f;
#pragma unroll
        for (int n = 0; n < 16; ++n) {
            float pr = ar[n] * ar[n] + ai[n] * ai[n];
            ez0 += (n & 8) ? -pr : pr;
            ez1 += (n & 4) ? -pr : pr;
            ez2 += (n & 2) ? -pr : pr;
            ez3 += (n & 1) ? -pr : pr;
        }
        smEz[t] = make_float4(ez0, ez1, ez2, ez3);
    }
    __syncthreads();

    // epilogue: thread owns oc group og..og+7; pixel varies over ch-loop so
    // consecutive lanes store consecutive uint4 (1 KB/instruction).
    const int og = (t & 15) * 8;
    const float4* fw4 = (const float4*)(ws + WS_FCW) + og;  // 8 float4
    const float*  fbp = ws + WS_FCB + og;
    float4 w0 = fw4[0], w1 = fw4[1], w2 = fw4[2], w3 = fw4[3];
    float4 w4 = fw4[4], w5 = fw4[5], w6 = fw4[6], w7 = fw4[7];
    float4 bA = *(const float4*)fbp, bB = *(const float4*)(fbp + 4);
#pragma unroll
    for (int ch = 0; ch < 4; ++ch) {
        const int pl = (t >> 4) + ch * 16;   // pixel within block
        const float4 ez = smEz[pl];
        float v0 = bA.x + ez.x*w0.x + ez.y*w0.y + ez.z*w0.z + ez.w*w0.w;
        float v1 = bA.y + ez.x*w1.x + ez.y*w1.y + ez.z*w1.z + ez.w*w1.w;
        float v2 = bA.z + ez.x*w2.x + ez.y*w2.y + ez.z*w2.z + ez.w*w2.w;
        float v3 = bA.w + ez.x*w3.x + ez.y*w3.y + ez.z*w3.z + ez.w*w3.w;
        float v4 = bB.x + ez.x*w4.x + ez.y*w4.y + ez.z*w4.z + ez.w*w4.w;
        float v5 = bB.y + ez.x*w5.x + ez.y*w5.y + ez.z*w5.z + ez.w*w5.w;
        float v6 = bB.z + ez.x*w6.x + ez.y*w6.y + ez.z*w6.z + ez.w*w6.w;
        float v7 = bB.w + ez.x*w7.x + ez.y*w7.y + ez.z*w7.z + ez.w*w7.w;
        if (bf) {
            u32 p0 = (u32)f2bf(v0) | ((u32)f2bf(v1) << 16);
            u32 p1 = (u32)f2bf(v2) | ((u32)f2bf(v3) << 16);
            u32 p2 = (u32)f2bf(v4) | ((u32)f2bf(v5) << 16);
            u32 p3 = (u32)f2bf(v6) | ((u32)f2bf(v7) << 16);
            ((uint4*)out)[blockIdx.x * 1024 + ch * 256 + t] =
                make_uint4(p0, p1, p2, p3);
        } else {
            float4* o = (float4*)out + (blockIdx.x * 2048 + ch * 512 + 2 * t);
            o[0] = make_float4(v0, v1, v2, v3);
            o[1] = make_float4(v4, v5, v6, v7);
        }
    }
}

extern "C" void kernel_launch(void* const* d_in, const int* in_sizes, int n_in,
                              void* d_out, int out_size, void* d_ws, size_t ws_size,
                              hipStream_t stream) {
    float* ws = (float*)d_ws;
    float4* part = (float4*)(ws + WS_PART);
    k0_prep<<<dim3(8), dim3(256), 0, stream>>>(d_in[0], d_in[1], d_in[2], d_in[3],
                                               d_in[4], d_in[5], d_in[6], ws);
    kA_conv<<<dim3(8192), dim3(256), 0, stream>>>(d_in[0], ws, part);
    kB_circuit_fc<<<dim3(1024), dim3(256), 0, stream>>>(ws, part, d_out);
}